// Round 1
// baseline (188.344 us; speedup 1.0000x reference)
//
#include <hip/hip_runtime.h>
#include <cmath>

// Problem constants (act: (4, 4096, 4096) float32, GROUP_SIZE = 32)
#define NELEM   (4ull * 4096ull * 4096ull)   // 67108864 elements
#define NV4     (NELEM / 4ull)               // 16777216 float4s
#define NGROUPS 128                          // 4096 / 32

// Pass 1: per-group global abs-max.
// Requirement: gridDim.x * blockDim.x must be a multiple of 1024 (float4s per
// row) so each thread's group index is invariant across grid-stride iters.
__global__ void pass1_max(const float4* __restrict__ in,
                          unsigned int* __restrict__ gmax) {
    __shared__ unsigned int smax[NGROUPS];
    const int tid = threadIdx.x;
    if (tid < NGROUPS) smax[tid] = 0u;
    __syncthreads();

    const size_t idx    = (size_t)blockIdx.x * blockDim.x + tid;
    const size_t stride = (size_t)gridDim.x * blockDim.x;   // multiple of 1024
    // float4 i covers float columns (4i mod 4096)..(4i mod 4096)+3 -> one group
    const int g = (int)((idx & 1023u) >> 3);

    float m = 0.0f;
    for (size_t i = idx; i < NV4; i += stride) {
        float4 v = in[i];
        float a = fmaxf(fmaxf(fabsf(v.x), fabsf(v.y)),
                        fmaxf(fabsf(v.z), fabsf(v.w)));
        m = fmaxf(m, a);
    }
    // non-negative float bit patterns order like uints
    atomicMax(&smax[g], __float_as_uint(m));
    __syncthreads();
    if (tid < NGROUPS) atomicMax(&gmax[tid], smax[tid]);
}

// Mid: exps + per-group (qstep = s/8, inv_s = 1/s), all exact powers of two.
__global__ void compute_scales(const unsigned int* __restrict__ gmax,
                               float* __restrict__ exps_out,
                               float2* __restrict__ scales) {
    const int g = threadIdx.x;
    if (g >= NGROUPS) return;
    const float m = __uint_as_float(gmax[g]);
    int e = 0;
    if (m > 0.0f) {
        int e2;
        (void)frexpf(m, &e2);   // m = f * 2^e2, f in [0.5, 1)
        e = e2 - 1;             // exact floor(log2(m))
    }
    exps_out[g] = (float)e;
    float2 sc;
    sc.x = ldexpf(1.0f, e - 3);  // s / 8
    sc.y = ldexpf(1.0f, -e);     // 1 / s
    scales[g] = sc;
}

// Pass 2: q = copysign(rint(min(|a| * inv_s, 1) * 8) * qstep, a)
__global__ void pass2_quant(const float4* __restrict__ in,
                            float4* __restrict__ out,
                            const float2* __restrict__ scales) {
    __shared__ float2 ssc[NGROUPS];
    const int tid = threadIdx.x;
    if (tid < NGROUPS) ssc[tid] = scales[tid];
    __syncthreads();

    const size_t idx    = (size_t)blockIdx.x * blockDim.x + tid;
    const size_t stride = (size_t)gridDim.x * blockDim.x;   // multiple of 1024
    const int g = (int)((idx & 1023u) >> 3);
    const float qstep = ssc[g].x;
    const float inv_s = ssc[g].y;

    for (size_t i = idx; i < NV4; i += stride) {
        float4 v = in[i];
        float4 q;
        q.x = copysignf(rintf(fminf(fabsf(v.x) * inv_s, 1.0f) * 8.0f) * qstep, v.x);
        q.y = copysignf(rintf(fminf(fabsf(v.y) * inv_s, 1.0f) * 8.0f) * qstep, v.y);
        q.z = copysignf(rintf(fminf(fabsf(v.z) * inv_s, 1.0f) * 8.0f) * qstep, v.z);
        q.w = copysignf(rintf(fminf(fabsf(v.w) * inv_s, 1.0f) * 8.0f) * qstep, v.w);
        out[i] = q;
    }
}

extern "C" void kernel_launch(void* const* d_in, const int* in_sizes, int n_in,
                              void* d_out, int out_size, void* d_ws, size_t ws_size,
                              hipStream_t stream) {
    const float* act = (const float*)d_in[0];
    float* q_out    = (float*)d_out;
    float* exps_out = q_out + NELEM;                       // 128 floats at tail

    unsigned int* gmax = (unsigned int*)d_ws;              // 128 * 4 B
    float2* scales = (float2*)((char*)d_ws + 512);         // 128 * 8 B

    // ws is poisoned 0xAA and never re-poisoned between replays: zero it every call.
    hipMemsetAsync(gmax, 0, NGROUPS * sizeof(unsigned int), stream);

    const int BLK = 256;
    const int GRID = 2048;   // 2048*256 = 524288 threads, multiple of 1024 ✓

    pass1_max<<<GRID, BLK, 0, stream>>>((const float4*)act, gmax);
    compute_scales<<<1, NGROUPS, 0, stream>>>(gmax, exps_out, scales);
    pass2_quant<<<GRID, BLK, 0, stream>>>((const float4*)act, (float4*)q_out, scales);
}

// Round 2
// 132.860 us; speedup vs baseline: 1.4176x; 1.4176x over previous
//
#include <hip/hip_runtime.h>
#include <cmath>

// act: (4, 4096, 4096) float32, GROUP_SIZE = 32
#define NELEM      (4ull * 4096ull * 4096ull)   // 67108864
#define NV4        (NELEM / 4ull)               // 16777216 float4s
#define NGROUPS    128                          // 4096 / 32
#define P1_BLOCKS  512
#define P1_THREADS 1024                         // 512*1024 = 524288 (mult of 1024)

typedef float v4f __attribute__((ext_vector_type(4)));

// ---------------------------------------------------------------------------
// Pass 1: per-(block,group) partial abs-max. blockDim=1024 so tid&1023 == tid
// and each thread's group g = tid>>3 is fixed across grid-stride iterations.
// No global atomics, no memset: every partial slot is written unconditionally.
// Normal (caching) loads on purpose: they warm L3 for pass 2's re-read.
__global__ void __launch_bounds__(P1_THREADS)
pass1_max(const float4* __restrict__ in, unsigned int* __restrict__ partials) {
    __shared__ unsigned int smax[NGROUPS];
    const int tid = threadIdx.x;
    if (tid < NGROUPS) smax[tid] = 0u;
    __syncthreads();

    const size_t idx    = (size_t)blockIdx.x * P1_THREADS + tid;
    const size_t stride = (size_t)P1_BLOCKS * P1_THREADS;   // 524288
    const int g = tid >> 3;                                 // 0..127

    float m = 0.0f;
    #pragma unroll 4
    for (size_t i = idx; i < NV4; i += stride) {            // 32 iters
        float4 v = in[i];
        m = fmaxf(m, fmaxf(fmaxf(fabsf(v.x), fabsf(v.y)),
                           fmaxf(fabsf(v.z), fabsf(v.w))));
    }
    // non-negative float bit patterns order like uints
    atomicMax(&smax[g], __float_as_uint(m));
    __syncthreads();
    if (tid < NGROUPS)
        partials[(size_t)blockIdx.x * NGROUPS + tid] = smax[tid];
}

// ---------------------------------------------------------------------------
// Reduce partials (512 x 128, 256 KB, L2-resident) -> exps + per-group
// (qstep = s/8, inv_s = 1/s), all exact powers of two.
__global__ void __launch_bounds__(1024)
reduce_scales(const unsigned int* __restrict__ partials,
              float* __restrict__ exps_out, float2* __restrict__ scales) {
    __shared__ unsigned int red[NGROUPS];
    const int tid = threadIdx.x;
    if (tid < NGROUPS) red[tid] = 0u;
    __syncthreads();

    const int g = tid & 127;
    const int c = tid >> 7;                 // 8 chunks of 64 blocks
    unsigned int m = 0u;
    #pragma unroll 8
    for (int b = c * 64; b < c * 64 + 64; ++b)
        m = max(m, partials[(size_t)b * NGROUPS + g]);
    atomicMax(&red[g], m);
    __syncthreads();

    if (tid < NGROUPS) {
        const float mf = __uint_as_float(red[tid]);
        int e = 0;
        if (mf > 0.0f) {
            int e2;
            (void)frexpf(mf, &e2);          // mf = f * 2^e2, f in [0.5,1)
            e = e2 - 1;                     // exact floor(log2(mf))
        }
        exps_out[tid] = (float)e;
        scales[tid] = make_float2(ldexpf(1.0f, e - 3),   // s/8
                                  ldexpf(1.0f, -e));     // 1/s
    }
}

// ---------------------------------------------------------------------------
// Pass 2: q = copysign(rint(min(|a|*inv_s,1)*8)*qstep, a).
// rintf -> v_rndne_f32 (round-half-even) matches jnp.round exactly; all
// scale multiplies are powers of two -> bit-exact vs the numpy reference.
// Output via NON-TEMPORAL stores so the write stream does not evict the
// L3-resident input that pass 1 just warmed.
__global__ void __launch_bounds__(256)
pass2_quant(const float4* __restrict__ in, float4* __restrict__ out,
            const float2* __restrict__ scales) {
    __shared__ float2 ssc[NGROUPS];
    const int tid = threadIdx.x;
    if (tid < NGROUPS) ssc[tid] = scales[tid];
    __syncthreads();

    const size_t idx    = (size_t)blockIdx.x * blockDim.x + tid;
    const size_t stride = (size_t)gridDim.x * blockDim.x;   // 524288
    const int g = (int)((idx & 1023u) >> 3);
    const float qstep = ssc[g].x;
    const float inv_s = ssc[g].y;

    for (size_t i = idx; i < NV4; i += stride) {
        float4 v = in[i];
        v4f q;
        q.x = copysignf(rintf(fminf(fabsf(v.x) * inv_s, 1.0f) * 8.0f) * qstep, v.x);
        q.y = copysignf(rintf(fminf(fabsf(v.y) * inv_s, 1.0f) * 8.0f) * qstep, v.y);
        q.z = copysignf(rintf(fminf(fabsf(v.z) * inv_s, 1.0f) * 8.0f) * qstep, v.z);
        q.w = copysignf(rintf(fminf(fabsf(v.w) * inv_s, 1.0f) * 8.0f) * qstep, v.w);
        __builtin_nontemporal_store(q, (v4f*)&out[i]);
    }
}

// ---------------------------------------------------------------------------
extern "C" void kernel_launch(void* const* d_in, const int* in_sizes, int n_in,
                              void* d_out, int out_size, void* d_ws, size_t ws_size,
                              hipStream_t stream) {
    const float* act = (const float*)d_in[0];
    float* q_out    = (float*)d_out;
    float* exps_out = q_out + NELEM;                        // 128 floats at tail

    unsigned int* partials = (unsigned int*)d_ws;           // 512*128*4 = 256 KB
    float2* scales = (float2*)((char*)d_ws + P1_BLOCKS * NGROUPS * sizeof(unsigned int));

    pass1_max<<<P1_BLOCKS, P1_THREADS, 0, stream>>>((const float4*)act, partials);
    reduce_scales<<<1, 1024, 0, stream>>>(partials, exps_out, scales);
    pass2_quant<<<2048, 256, 0, stream>>>((const float4*)act, (float4*)q_out, scales);
}